// Round 1
// baseline (117.155 us; speedup 1.0000x reference)
//
#include <hip/hip_runtime.h>

// Problem constants (must match reference)
#define L_SZ 100000
#define K_DIM 128
#define B_SZ 16384
#define CS_SZ 8
#define NS_SZ 20
#define NEPOCH 10
#define LOG_SQRT_2PI 0.9189385332046727

// ---- likelihood kernel ------------------------------------------------------
// 2048 blocks x 256 threads. Each wave (4/block, 8192 total) handles 2 batch
// elements. Lane l holds dims {2l, 2l+1} of the K=128 vector via float2 loads
// (one fully-coalesced 512B load per row per wave).
__global__ __launch_bounds__(256) void ll_kernel(
    const int* __restrict__ contexts, const int* __restrict__ targets,
    const int* __restrict__ neg_idx, const float* __restrict__ tW,
    const float* __restrict__ cW, double* __restrict__ partials)
{
    const int lane = threadIdx.x & 63;
    const int wave = threadIdx.x >> 6;
    const int gw = blockIdx.x * 4 + wave;   // 0..8191

    float lacc = 0.0f;
    #pragma unroll
    for (int rep = 0; rep < 2; ++rep) {
        const int b = gw + rep * 8192;

        // ctx_sum (lane's 2 dims)
        float sx = 0.0f, sy = 0.0f;
        #pragma unroll
        for (int c = 0; c < CS_SZ; ++c) {
            const int idx = contexts[b * CS_SZ + c];
            const float2 v = *reinterpret_cast<const float2*>(
                &cW[(size_t)idx * K_DIM + lane * 2]);
            sx += v.x; sy += v.y;
        }

        // positive target: -softplus(-eta) contributes softplus(-eta) to loss
        {
            const int t = targets[b];
            const float2 v = *reinterpret_cast<const float2*>(
                &tW[(size_t)t * K_DIM + lane * 2]);
            float p = v.x * sx + v.y * sy;
            #pragma unroll
            for (int o = 32; o; o >>= 1) p += __shfl_xor(p, o, 64);
            // all lanes now hold full eta; softplus computed redundantly (uniform)
            lacc += (lane == 0) ? (fmaxf(-p, 0.0f) + log1pf(__expf(-fabsf(p)))) : 0.0f;
        }

        // negative targets: softplus(+eta)
        #pragma unroll
        for (int n = 0; n < NS_SZ; ++n) {
            const int t = neg_idx[b * NS_SZ + n];
            const float2 v = *reinterpret_cast<const float2*>(
                &tW[(size_t)t * K_DIM + lane * 2]);
            float p = v.x * sx + v.y * sy;
            #pragma unroll
            for (int o = 32; o; o >>= 1) p += __shfl_xor(p, o, 64);
            lacc += (lane == 0) ? (fmaxf(p, 0.0f) + log1pf(__expf(-fabsf(p)))) : 0.0f;
        }
    }

    __shared__ float sdata[4];
    if (lane == 0) sdata[wave] = lacc;
    __syncthreads();
    if (threadIdx.x == 0)
        partials[blockIdx.x] = (double)(sdata[0] + sdata[1] + sdata[2] + sdata[3]);
}

// ---- prior kernel: sum of squares over both weight tables -------------------
__global__ __launch_bounds__(256) void prior_kernel(
    const float* __restrict__ tW, const float* __restrict__ cW,
    double* __restrict__ partials)
{
    const int NT4 = (L_SZ * K_DIM) / 4;          // 3,200,000
    const int NC4 = ((L_SZ + 1) * K_DIM) / 4;    // 3,200,032
    const int tid = blockIdx.x * blockDim.x + threadIdx.x;
    const int stride = gridDim.x * blockDim.x;

    float acc = 0.0f;
    const float4* t4 = reinterpret_cast<const float4*>(tW);
    for (int i = tid; i < NT4; i += stride) {
        const float4 v = t4[i];
        acc += v.x * v.x + v.y * v.y + v.z * v.z + v.w * v.w;
    }
    const float4* c4 = reinterpret_cast<const float4*>(cW);
    for (int i = tid; i < NC4; i += stride) {
        const float4 v = c4[i];
        acc += v.x * v.x + v.y * v.y + v.z * v.z + v.w * v.w;
    }

    __shared__ float sdata[256];
    sdata[threadIdx.x] = acc;
    __syncthreads();
    for (int s = 128; s > 0; s >>= 1) {
        if (threadIdx.x < s) sdata[threadIdx.x] += sdata[threadIdx.x + s];
        __syncthreads();
    }
    if (threadIdx.x == 0) partials[blockIdx.x] = (double)sdata[0];
}

// ---- finalize: reduce partials, assemble scalar loss ------------------------
__global__ __launch_bounds__(256) void finalize_kernel(
    const double* __restrict__ pll, int nll,
    const double* __restrict__ pprior, int nprior,
    float* __restrict__ out)
{
    double a = 0.0, p = 0.0;
    for (int i = threadIdx.x; i < nll; i += 256) a += pll[i];
    for (int i = threadIdx.x; i < nprior; i += 256) p += pprior[i];

    __shared__ double sA[256], sP[256];
    sA[threadIdx.x] = a; sP[threadIdx.x] = p;
    __syncthreads();
    for (int s = 128; s > 0; s >>= 1) {
        if (threadIdx.x < s) {
            sA[threadIdx.x] += sA[threadIdx.x + s];
            sP[threadIdx.x] += sP[threadIdx.x + s];
        }
        __syncthreads();
    }
    if (threadIdx.x == 0) {
        // loss = -(NEPOCH*LL + log_prior)
        //      = NEPOCH * sum(softplus terms) + 0.5*sum(x^2) + count*LOG_SQRT_2PI
        const double C = (double)((2LL * L_SZ + 1) * K_DIM) * LOG_SQRT_2PI;
        const double loss = (double)NEPOCH * sA[0] + 0.5 * sP[0] + C;
        out[0] = (float)loss;
    }
}

extern "C" void kernel_launch(void* const* d_in, const int* in_sizes, int n_in,
                              void* d_out, int out_size, void* d_ws, size_t ws_size,
                              hipStream_t stream) {
    const int*   contexts = (const int*)d_in[0];
    const int*   targets  = (const int*)d_in[1];
    const int*   neg_idx  = (const int*)d_in[2];
    const float* tW       = (const float*)d_in[3];
    const float* cW       = (const float*)d_in[4];
    float* out = (float*)d_out;

    double* pll    = (double*)d_ws;   // 2048 doubles
    double* pprior = pll + 2048;      // 1024 doubles

    ll_kernel<<<2048, 256, 0, stream>>>(contexts, targets, neg_idx, tW, cW, pll);
    prior_kernel<<<1024, 256, 0, stream>>>(tW, cW, pprior);
    finalize_kernel<<<1, 256, 0, stream>>>(pll, 2048, pprior, 1024, out);
}

// Round 2
// 58.721 us; speedup vs baseline: 1.9951x; 1.9951x over previous
//
#include <hip/hip_runtime.h>

// Problem constants (must match reference)
#define L_SZ 100000
#define K_DIM 128
#define B_SZ 16384
#define CS_SZ 8
#define NS_SZ 20
#define NEPOCH 10
#define LOG_SQRT_2PI 0.9189385332046727

// softplus(x) = max(x,0) + log(1 + exp(-|x|)); fast-math variant is fine:
// tolerance is ~2% relative on a ~2.6e7 loss.
__device__ __forceinline__ float softplus_f(float x) {
    return fmaxf(x, 0.0f) + __logf(1.0f + __expf(-fabsf(x)));
}

// ---- fused likelihood + prior kernel ---------------------------------------
// 2048 blocks x 256 threads (4 waves). Each wave handles 2 batch elements.
// Within a wave: 4 groups of 16 lanes; lane (g, j) holds dims j*8..j*8+7.
// Group g owns targets n with n%4 == g (n=0 is the positive target).
// After the 4-step intra-group reduce, slot lane j==s keeps eta; a single
// softplus per lane per batch element covers all 21 targets.
__global__ __launch_bounds__(256) void fused_kernel(
    const int* __restrict__ contexts, const int* __restrict__ targets,
    const int* __restrict__ neg_idx, const float* __restrict__ tW,
    const float* __restrict__ cW,
    double* __restrict__ pll, double* __restrict__ pprior)
{
    const int lane = threadIdx.x & 63;
    const int wave = threadIdx.x >> 6;
    const int j = lane & 15;      // position within 16-lane group
    const int g = lane >> 4;      // group 0..3
    const int gw = blockIdx.x * 4 + wave;   // 0..8191

    const int n_mine = 4 * j + g;           // the target this lane softpluses
    const bool valid = (n_mine < 21);
    const float sgn = (n_mine == 0) ? -1.0f : 1.0f;  // pos target: softplus(-eta)

    float lacc = 0.0f;

    #pragma unroll
    for (int rep = 0; rep < 2; ++rep) {
        // wave-uniform batch index -> SGPR so index loads become s_load
        const int b = __builtin_amdgcn_readfirstlane(gw + rep * 8192);

        // ctx_sum dims j*8..j*8+7 (identical across the 4 groups; lanes
        // j, j+16, j+32, j+48 load the same 32B -> hardware broadcast)
        float4 s0 = {0.f, 0.f, 0.f, 0.f}, s1 = {0.f, 0.f, 0.f, 0.f};
        #pragma unroll
        for (int c = 0; c < CS_SZ; ++c) {
            const int idx = contexts[b * CS_SZ + c];
            const float4* r = reinterpret_cast<const float4*>(
                &cW[(size_t)idx * K_DIM + j * 8]);
            const float4 a = r[0], d = r[1];
            s0.x += a.x; s0.y += a.y; s0.z += a.z; s0.w += a.w;
            s1.x += d.x; s1.y += d.y; s1.z += d.z; s1.w += d.w;
        }

        // dot products: group g handles targets n = 4*s + g, s = 0..5
        float keep = 0.0f;
        #pragma unroll
        for (int s = 0; s < 6; ++s) {
            const int n = 4 * s + g;
            if (n < 21) {
                const int t = (n == 0) ? targets[b]
                                       : neg_idx[b * NS_SZ + (n - 1)];
                const float4* r = reinterpret_cast<const float4*>(
                    &tW[(size_t)t * K_DIM + j * 8]);
                const float4 a = r[0], d = r[1];
                float p = a.x * s0.x + a.y * s0.y + a.z * s0.z + a.w * s0.w
                        + d.x * s1.x + d.y * s1.y + d.z * s1.z + d.w * s1.w;
                // reduce across the 16-lane group (ds_swizzle path)
                p += __shfl_xor(p, 1, 16);
                p += __shfl_xor(p, 2, 16);
                p += __shfl_xor(p, 4, 16);
                p += __shfl_xor(p, 8, 16);
                keep = (j == s) ? p : keep;
            }
        }
        // one softplus per lane per batch element (covers its one target)
        lacc += valid ? softplus_f(sgn * keep) : 0.0f;
    }

    // ---- prior phase: grid-stride sum of squares over both tables ----------
    const int NT4 = (L_SZ * K_DIM) / 4;          // 3,200,000
    const int NC4 = ((L_SZ + 1) * K_DIM) / 4;    // 3,200,032
    const int tid = blockIdx.x * blockDim.x + threadIdx.x;
    const int stride = gridDim.x * blockDim.x;

    float pacc = 0.0f;
    const float4* t4 = reinterpret_cast<const float4*>(tW);
    for (int i = tid; i < NT4; i += stride) {
        const float4 v = t4[i];
        pacc += v.x * v.x + v.y * v.y + v.z * v.z + v.w * v.w;
    }
    const float4* c4 = reinterpret_cast<const float4*>(cW);
    for (int i = tid; i < NC4; i += stride) {
        const float4 v = c4[i];
        pacc += v.x * v.x + v.y * v.y + v.z * v.z + v.w * v.w;
    }

    // ---- per-wave then per-block reduction ---------------------------------
    #pragma unroll
    for (int o = 32; o; o >>= 1) {
        lacc += __shfl_xor(lacc, o, 64);
        pacc += __shfl_xor(pacc, o, 64);
    }
    __shared__ float sl[4], sp[4];
    if (lane == 0) { sl[wave] = lacc; sp[wave] = pacc; }
    __syncthreads();
    if (threadIdx.x == 0) {
        pll[blockIdx.x]    = (double)(sl[0] + sl[1] + sl[2] + sl[3]);
        pprior[blockIdx.x] = (double)(sp[0] + sp[1] + sp[2] + sp[3]);
    }
}

// ---- finalize: reduce partials, assemble scalar loss ------------------------
__global__ __launch_bounds__(256) void finalize_kernel(
    const double* __restrict__ pll, int nll,
    const double* __restrict__ pprior, int nprior,
    float* __restrict__ out)
{
    double a = 0.0, p = 0.0;
    for (int i = threadIdx.x; i < nll; i += 256) a += pll[i];
    for (int i = threadIdx.x; i < nprior; i += 256) p += pprior[i];

    __shared__ double sA[256], sP[256];
    sA[threadIdx.x] = a; sP[threadIdx.x] = p;
    __syncthreads();
    for (int s = 128; s > 0; s >>= 1) {
        if (threadIdx.x < s) {
            sA[threadIdx.x] += sA[threadIdx.x + s];
            sP[threadIdx.x] += sP[threadIdx.x + s];
        }
        __syncthreads();
    }
    if (threadIdx.x == 0) {
        // loss = NEPOCH * sum(softplus terms) + 0.5*sum(x^2) + count*LOG_SQRT_2PI
        const double C = (double)((2LL * L_SZ + 1) * K_DIM) * LOG_SQRT_2PI;
        const double loss = (double)NEPOCH * sA[0] + 0.5 * sP[0] + C;
        out[0] = (float)loss;
    }
}

extern "C" void kernel_launch(void* const* d_in, const int* in_sizes, int n_in,
                              void* d_out, int out_size, void* d_ws, size_t ws_size,
                              hipStream_t stream) {
    const int*   contexts = (const int*)d_in[0];
    const int*   targets  = (const int*)d_in[1];
    const int*   neg_idx  = (const int*)d_in[2];
    const float* tW       = (const float*)d_in[3];
    const float* cW       = (const float*)d_in[4];
    float* out = (float*)d_out;

    double* pll    = (double*)d_ws;   // 2048 doubles
    double* pprior = pll + 2048;      // 2048 doubles

    fused_kernel<<<2048, 256, 0, stream>>>(contexts, targets, neg_idx,
                                           tW, cW, pll, pprior);
    finalize_kernel<<<1, 256, 0, stream>>>(pll, 2048, pprior, 2048, out);
}